// Round 11
// baseline (114.012 us; speedup 1.0000x reference)
//
#include <hip/hip_runtime.h>

#define GX 192
#define GY 96
#define GZ 192
#define GRP (GY*GZ)            // 18432 (y,z) groups
#define NVOX (GX*GRP)          // 3538944 voxels

#define NXC 12                 // x-chunks in prep
#define XCW (GX/NXC)           // 16 voxels per thread/chunk
#define GBLK (GRP/256)         // 72 blocks per chunk

#define SB   (GRP/256)         // 72 sum/select blocks, 256 groups each
#define SGPT (GRP/256)         // 72 groups per thread in select scans

// workspace byte offsets
#define WS_MVP    0                        // 16 floats
#define WS_G16    64                       // GRP x 16B records {pad u32, u8 cnt[12]}
#define WS_DEPTH  (WS_G16 + (size_t)GRP*16)// GRP u32 depth bits (for k_out)
#define WS_CSUM   (WS_DEPTH + GRP*4)       // GRP u8 summed counts
#define WS_DONE   (WS_CSUM + GRP)          // 1 u32 block-done counter
#define WS_SEL    (WS_DONE + 16)           // 2 u32: T, R
#define WS_TLIST  (WS_SEL + 16)            // 256 u32 tied group ids (sorted)
#define WS_TPREF  (WS_TLIST + 1024)        // GX u32 excl prefix of tied-valid per x
#define WS_NTIED  (WS_TPREF + GX*4)        // 1 u32

typedef float f4 __attribute__((ext_vector_type(4)));

#define BSUM(w) (((w) & 255u) + (((w) >> 8) & 255u) + (((w) >> 16) & 255u) + ((w) >> 24))

// Replicate reference fp32 arithmetic exactly:
//   clip_c = fma(cz, M[c][2], fma(cy, M[c][1], cx*M[c][0])) + M[c][3]
__device__ __forceinline__ bool voxel_valid(int x, int g,
                                            const float* __restrict__ occL,
                                            const float* M,
                                            float* occ_out)
{
    int y = g / GZ;
    int z = g - y * GZ;
    float cx = (float)(2 * x - 191);
    float cy = (float)(2 * y + 1);
    float cz = (float)(2 * z - 191);

    float logit = occL[(size_t)x * GRP + g];
    float occ = 1.0f / (1.0f + expf(-logit));
    *occ_out = occ;
    if (!(occ > 0.01f)) return false;

    float c0 = __fadd_rn(__fmaf_rn(cz, M[2],  __fmaf_rn(cy, M[1],  __fmul_rn(cx, M[0]))),  M[3]);
    float c1 = __fadd_rn(__fmaf_rn(cz, M[6],  __fmaf_rn(cy, M[5],  __fmul_rn(cx, M[4]))),  M[7]);
    float c2 = __fadd_rn(__fmaf_rn(cz, M[10], __fmaf_rn(cy, M[9],  __fmul_rn(cx, M[8]))),  M[11]);
    float c3 = __fadd_rn(__fmaf_rn(cz, M[14], __fmaf_rn(cy, M[13], __fmul_rn(cx, M[12]))), M[15]);

    float w  = fmaxf(c3, 1e-6f);
    float nx = c0 / w;
    float ny = c1 / w;
    float nz = c2 / w;
    return (nx >= -1.0f) && (nx <= 1.0f) &&
           (ny >= -1.0f) && (ny <= 1.0f) &&
           (nz >= -1.0f) && (nz <= 1.0f);
}

// depth bits for group g — identical pinned-FMA expression everywhere.
__device__ __forceinline__ unsigned depth_bits(int g, float v8, float v9,
                                               float v10, float v11)
{
    int y = g / GZ;
    int z = g - y * GZ;
    float cy = (float)(2 * y + 1);
    float cz = (float)(2 * z - 191);
    float seed = __fmul_rn(-191.0f, v8);
    float vz = __fadd_rn(__fmaf_rn(cz, v10, __fmaf_rn(cy, v9, seed)), v11);
    return __float_as_uint(fmaxf(-vz, 0.0f));   // >= 0: bits order-monotone
}

__device__ __forceinline__ void compute_mvp_lds(const float* view, const float* proj,
                                                float* s_mvp, int tid)
{
    if (tid < 16) {
        int r = tid >> 2, c = tid & 3;
        float acc = 0.0f;
        for (int k = 0; k < 4; ++k)
            acc = __fadd_rn(acc, __fmul_rn(proj[r * 4 + k], view[k * 4 + c]));
        s_mvp[tid] = acc;
    }
}

__device__ __forceinline__ unsigned wave_incl_scan(unsigned v, int lane)
{
    #pragma unroll
    for (int off = 1; off < 64; off <<= 1) {
        unsigned u = (unsigned)__shfl_up((int)v, off);
        if (lane >= off) v += u;
    }
    return v;
}

// K1: mvp (block 0), done-counter zero (block 0), depth bits (xc==0),
// u8 partial valid counts into bytes 4..15 of the 16B group record.
// grid = NXC * GBLK = 864 blocks of 256.
__global__ __launch_bounds__(256) void k_prep_count(
    const float* __restrict__ view, const float* __restrict__ proj,
    const float* __restrict__ occL,
    float* __restrict__ mvpOut,
    unsigned char* __restrict__ g16,
    unsigned* __restrict__ depthBits,
    unsigned* __restrict__ doneCnt)
{
    __shared__ float s_mvp[16];
    int tid = threadIdx.x;
    compute_mvp_lds(view, proj, s_mvp, tid);
    __syncthreads();

    int b  = blockIdx.x;
    int gb = b % GBLK;
    int xc = b / GBLK;
    int g  = gb * 256 + tid;

    if (b == 0) {
        if (tid < 16) mvpOut[tid] = s_mvp[tid];
        if (tid == 0) *doneCnt = 0u;
    }

    if (xc == 0)
        depthBits[g] = depth_bits(g, view[8], view[9], view[10], view[11]);

    unsigned c = 0;
    int x0 = xc * XCW;
    #pragma unroll
    for (int j = 0; j < XCW; ++j) {
        float occ;
        if (voxel_valid(x0 + j, g, occL, s_mvp, &occ)) ++c;
    }
    g16[(size_t)g * 16 + 4 + xc] = (unsigned char)c;
}

// K2: parallel count-sum (72 blocks) + last-block-done selection.
// Selection = verified 4x8-bit weighted radix walk; depth recomputed in VALU;
// counts from the 18 KB cnt8sum (L1-resident on the selecting CU).
__global__ __launch_bounds__(256) void k_sumsel(
    const float* __restrict__ view, const float* __restrict__ proj,
    const float* __restrict__ occL,
    const unsigned char* __restrict__ g16,
    unsigned char* __restrict__ cnt8sum,
    unsigned* __restrict__ doneCnt,
    const int* __restrict__ maxBlocksPtr,
    unsigned* __restrict__ sel,
    unsigned* __restrict__ tiedList,
    unsigned* __restrict__ tiedPrefX,
    unsigned* __restrict__ nTiedG)
{
    __shared__ unsigned s_last;
    __shared__ float s_mvp[16];
    __shared__ unsigned s_h[256];
    __shared__ unsigned s_w[4];
    __shared__ unsigned s_tot;
    __shared__ unsigned s_prefix, s_remK;
    __shared__ unsigned s_list[256];
    __shared__ int s_n;
    __shared__ unsigned s_cntX[GX];

    int tid = threadIdx.x;
    int g0  = blockIdx.x * 256 + tid;

    // parallel part: sum 12 u8 partials -> one u8 per group
    uint4 q = *(const uint4*)(g16 + (size_t)g0 * 16);
    cnt8sum[g0] = (unsigned char)(BSUM(q.y) + BSUM(q.z) + BSUM(q.w));

    __threadfence();
    if (tid == 0) {
        unsigned old = atomicAdd(doneCnt, 1u);
        s_last = (old == SB - 1) ? 1u : 0u;
    }
    __syncthreads();
    if (!s_last) return;
    __threadfence();                       // acquire: see all blocks' cnt8sum

    // ---- last block: full selection ----
    compute_mvp_lds(view, proj, s_mvp, tid);
    float v8 = view[8], v9 = view[9], v10 = view[10], v11 = view[11];
    int lane = tid & 63;
    int wid  = tid >> 6;
    unsigned K = (unsigned)maxBlocksPtr[0];

    unsigned prefix = 0, remK = K;
    for (int p = 0; p < 4; ++p) {
        int shift = 24 - 8 * p;
        s_h[tid] = 0;
        __syncthreads();
        for (int j = 0; j < SGPT; ++j) {
            int g = tid + j * 256;
            unsigned cc = cnt8sum[g];
            if (!cc) continue;
            unsigned db = depth_bits(g, v8, v9, v10, v11);
            if (p > 0 && (db >> (shift + 8)) != prefix) continue;
            atomicAdd(&s_h[(db >> shift) & 255u], cc);
        }
        __syncthreads();
        unsigned ps = s_h[tid];
        unsigned iw = wave_incl_scan(ps, lane);
        if (lane == 63) s_w[wid] = iw;
        __syncthreads();
        if (wid == 0) {
            unsigned wv = (lane < 4) ? s_w[lane] : 0u;
            unsigned wiw = wave_incl_scan(wv, lane);
            if (lane < 4) s_w[lane] = wiw - wv;   // exclusive wave offset
            if (lane == 3) s_tot = wiw;           // pass total
        }
        __syncthreads();
        unsigned incl = iw + s_w[wid];
        unsigned excl = incl - ps;

        if (p == 0) {
            if (s_tot <= K) {                     // keep all valid (uniform)
                if (tid == 0) {
                    sel[0] = 0xFFFFFFFFu;
                    sel[1] = 0x7FFFFFFFu;
                    *nTiedG = 0u;
                }
                return;
            }
        }
        if (excl < remK && remK <= incl) {        // unique crossing thread
            s_prefix = (prefix << 8) | (unsigned)tid;
            s_remK   = remK - excl;
        }
        __syncthreads();
        prefix = s_prefix; remK = s_remK;
        __syncthreads();
    }
    unsigned T = prefix;                          // threshold depth bits
    unsigned R = remK;                            // quota at exactly T

    // tied groups: sorted list + per-x valid prefix (occL recompute)
    if (tid == 0) s_n = 0;
    if (tid < GX) s_cntX[tid] = 0;
    __syncthreads();
    for (int j = 0; j < SGPT; ++j) {
        int g = tid + j * 256;
        if (depth_bits(g, v8, v9, v10, v11) == T) {
            int idx = atomicAdd(&s_n, 1);
            if (idx < 256) s_list[idx] = (unsigned)g;
        }
    }
    __syncthreads();
    int n = min(s_n, 256);
    if (tid == 0) {
        for (int a = 1; a < n; ++a) {             // insertion sort (n tiny)
            unsigned v = s_list[a];
            int b2 = a - 1;
            while (b2 >= 0 && s_list[b2] > v) { s_list[b2 + 1] = s_list[b2]; --b2; }
            s_list[b2 + 1] = v;
        }
    }
    __syncthreads();
    int pairs = GX * n;
    for (int pr = tid; pr < pairs; pr += 256) {
        int x = pr / n;
        int s = pr - x * n;
        float occ;
        if (voxel_valid(x, (int)s_list[s], occL, s_mvp, &occ))
            atomicAdd(&s_cntX[x], 1u);
    }
    __syncthreads();
    if (tid == 0) {
        unsigned run = 0;
        for (int x = 0; x < GX; ++x) { tiedPrefX[x] = run; run += s_cntX[x]; }
        *nTiedG = (unsigned)n;
        sel[0] = T;
        sel[1] = R;
    }
    if (tid < n) tiedList[tid] = s_list[tid];
}

// K3: output — R5-exact body (recompute predicate from occL; NT loads/stores).
__global__ __launch_bounds__(256) void k_out(
    const float* __restrict__ occL,
    const float* __restrict__ matL,
    const float* __restrict__ mvp,
    const unsigned* __restrict__ depthBits,
    const unsigned* __restrict__ sel,
    const unsigned* __restrict__ tiedList,
    const unsigned* __restrict__ tiedPrefX,
    const unsigned* __restrict__ nTiedPtr,
    float* __restrict__ out)
{
    int i = blockIdx.x * 256 + threadIdx.x;
    if (i >= NVOX) return;
    int x = i / GRP;
    int g = i - x * GRP;

    float occ;
    bool valid = voxel_valid(x, g, occL, mvp, &occ);
    bool keep = false;
    if (valid) {
        unsigned T  = sel[0];
        unsigned db = depthBits[g];
        if (db < T) {
            keep = true;
        } else if (db == T) {
            unsigned R = sel[1];
            unsigned rank = tiedPrefX[x];
            int n = (int)*nTiedPtr;
            for (int s = 0; s < n; ++s) {
                unsigned gs = tiedList[s];
                if (gs >= (unsigned)g) break;
                float o2;
                if (voxel_valid(x, (int)gs, occL, mvp, &o2)) ++rank;
            }
            keep = rank < R;
        }
    }

    f4 o0 = (f4)(0.0f);
    f4 o1 = (f4)(0.0f);
    if (keep) {
        const f4* mp = reinterpret_cast<const f4*>(matL) + (size_t)i * 2;
        f4 a = __builtin_nontemporal_load(mp);
        f4 b = __builtin_nontemporal_load(mp + 1);
        float mx = fmaxf(fmaxf(fmaxf(a[0], a[1]), fmaxf(a[2], a[3])),
                         fmaxf(fmaxf(b[0], b[1]), fmaxf(b[2], b[3])));
        float e0 = expf(a[0] - mx), e1 = expf(a[1] - mx), e2 = expf(a[2] - mx), e3 = expf(a[3] - mx);
        float e4 = expf(b[0] - mx), e5 = expf(b[1] - mx), e6 = expf(b[2] - mx), e7 = expf(b[3] - mx);
        float s = ((e0 + e1) + (e2 + e3)) + ((e4 + e5) + (e6 + e7));
        float inv = occ / s;
        o0[0] = e0 * inv; o0[1] = e1 * inv; o0[2] = e2 * inv; o0[3] = e3 * inv;
        o1[0] = e4 * inv; o1[1] = e5 * inv; o1[2] = e6 * inv; o1[3] = e7 * inv;
    }
    f4* op = reinterpret_cast<f4*>(out) + (size_t)i * 2;
    __builtin_nontemporal_store(o0, op);
    __builtin_nontemporal_store(o1, op + 1);
}

extern "C" void kernel_launch(void* const* d_in, const int* in_sizes, int n_in,
                              void* d_out, int out_size, void* d_ws, size_t ws_size,
                              hipStream_t stream)
{
    const float* occL = (const float*)d_in[0];
    const float* matL = (const float*)d_in[1];
    const float* view = (const float*)d_in[2];
    const float* proj = (const float*)d_in[3];
    const int*   mb   = (const int*)d_in[4];

    char* ws = (char*)d_ws;
    float*          mvp      = (float*)(ws + WS_MVP);
    unsigned char*  g16      = (unsigned char*)(ws + WS_G16);
    unsigned*       depthB   = (unsigned*)(ws + WS_DEPTH);
    unsigned char*  csum     = (unsigned char*)(ws + WS_CSUM);
    unsigned*       done     = (unsigned*)(ws + WS_DONE);
    unsigned*       sel      = (unsigned*)(ws + WS_SEL);
    unsigned*       tiedList = (unsigned*)(ws + WS_TLIST);
    unsigned*       tiedPref = (unsigned*)(ws + WS_TPREF);
    unsigned*       nTied    = (unsigned*)(ws + WS_NTIED);

    k_prep_count<<<NXC * GBLK, 256, 0, stream>>>(view, proj, occL, mvp, g16, depthB, done);
    k_sumsel<<<SB, 256, 0, stream>>>(view, proj, occL, g16, csum, done, mb,
                                     sel, tiedList, tiedPref, nTied);
    k_out<<<NVOX / 256, 256, 0, stream>>>(occL, matL, mvp, depthB, sel,
                                          tiedList, tiedPref, nTied, (float*)d_out);
}

// Round 12
// 91.071 us; speedup vs baseline: 1.2519x; 1.2519x over previous
//
#include <hip/hip_runtime.h>

#define GX 192
#define GY 96
#define GZ 192
#define GRP (GY*GZ)            // 18432 (y,z) groups
#define NVOX (GX*GRP)          // 3538944 voxels

#define NXC 12                 // x-chunks in prep
#define XCW (GX/NXC)           // 16 voxels per thread/chunk
#define GBLK (GRP/256)         // 72 blocks per chunk

#define SB   (GRP/256)         // 72 sum/select blocks
#define SGPT (GRP/256)         // 72 groups per thread in select (contiguous)

// workspace byte offsets
#define WS_MVP    0                        // 16 floats
#define WS_G16    64                       // GRP x 16B records {pad u32, u8 cnt[12]}
#define WS_DEPTH  (WS_G16 + (size_t)GRP*16)// GRP u32 depth bits (for k_out)
#define WS_CSUM   (WS_DEPTH + GRP*4)       // GRP u8 summed counts
#define WS_DONE   (WS_CSUM + GRP)          // 1 u32 block-done counter
#define WS_SEL    (WS_DONE + 16)           // 2 u32: T, R
#define WS_TLIST  (WS_SEL + 16)            // 256 u32 tied group ids (sorted)
#define WS_TPREF  (WS_TLIST + 1024)        // GX u32 excl prefix of tied-valid per x
#define WS_NTIED  (WS_TPREF + GX*4)        // 1 u32

typedef float f4 __attribute__((ext_vector_type(4)));

#define BSUM(w) (((w) & 255u) + (((w) >> 8) & 255u) + (((w) >> 16) & 255u) + ((w) >> 24))

// Replicate reference fp32 arithmetic exactly:
//   clip_c = fma(cz, M[c][2], fma(cy, M[c][1], cx*M[c][0])) + M[c][3]
__device__ __forceinline__ bool voxel_valid(int x, int g,
                                            const float* __restrict__ occL,
                                            const float* M,
                                            float* occ_out)
{
    int y = g / GZ;
    int z = g - y * GZ;
    float cx = (float)(2 * x - 191);
    float cy = (float)(2 * y + 1);
    float cz = (float)(2 * z - 191);

    float logit = occL[(size_t)x * GRP + g];
    float occ = 1.0f / (1.0f + expf(-logit));
    *occ_out = occ;
    if (!(occ > 0.01f)) return false;

    float c0 = __fadd_rn(__fmaf_rn(cz, M[2],  __fmaf_rn(cy, M[1],  __fmul_rn(cx, M[0]))),  M[3]);
    float c1 = __fadd_rn(__fmaf_rn(cz, M[6],  __fmaf_rn(cy, M[5],  __fmul_rn(cx, M[4]))),  M[7]);
    float c2 = __fadd_rn(__fmaf_rn(cz, M[10], __fmaf_rn(cy, M[9],  __fmul_rn(cx, M[8]))),  M[11]);
    float c3 = __fadd_rn(__fmaf_rn(cz, M[14], __fmaf_rn(cy, M[13], __fmul_rn(cx, M[12]))), M[15]);

    float w  = fmaxf(c3, 1e-6f);
    float nx = c0 / w;
    float ny = c1 / w;
    float nz = c2 / w;
    return (nx >= -1.0f) && (nx <= 1.0f) &&
           (ny >= -1.0f) && (ny <= 1.0f) &&
           (nz >= -1.0f) && (nz <= 1.0f);
}

// depth bits for group g — identical pinned-FMA expression everywhere.
__device__ __forceinline__ unsigned depth_bits(int g, float v8, float v9,
                                               float v10, float v11)
{
    int y = g / GZ;
    int z = g - y * GZ;
    float cy = (float)(2 * y + 1);
    float cz = (float)(2 * z - 191);
    float seed = __fmul_rn(-191.0f, v8);
    float vz = __fadd_rn(__fmaf_rn(cz, v10, __fmaf_rn(cy, v9, seed)), v11);
    return __float_as_uint(fmaxf(-vz, 0.0f));   // >= 0: bits order-monotone
}

__device__ __forceinline__ void compute_mvp_lds(const float* view, const float* proj,
                                                float* s_mvp, int tid)
{
    if (tid < 16) {
        int r = tid >> 2, c = tid & 3;
        float acc = 0.0f;
        for (int k = 0; k < 4; ++k)
            acc = __fadd_rn(acc, __fmul_rn(proj[r * 4 + k], view[k * 4 + c]));
        s_mvp[tid] = acc;
    }
}

__device__ __forceinline__ unsigned wave_incl_scan(unsigned v, int lane)
{
    #pragma unroll
    for (int off = 1; off < 64; off <<= 1) {
        unsigned u = (unsigned)__shfl_up((int)v, off);
        if (lane >= off) v += u;
    }
    return v;
}

// K1: mvp (block 0), done-counter zero (block 0), depth bits (xc==0),
// u8 partial valid counts into bytes 4..15 of the 16B group record.
__global__ __launch_bounds__(256) void k_prep_count(
    const float* __restrict__ view, const float* __restrict__ proj,
    const float* __restrict__ occL,
    float* __restrict__ mvpOut,
    unsigned char* __restrict__ g16,
    unsigned* __restrict__ depthBits,
    unsigned* __restrict__ doneCnt)
{
    __shared__ float s_mvp[16];
    int tid = threadIdx.x;
    compute_mvp_lds(view, proj, s_mvp, tid);
    __syncthreads();

    int b  = blockIdx.x;
    int gb = b % GBLK;
    int xc = b / GBLK;
    int g  = gb * 256 + tid;

    if (b == 0) {
        if (tid < 16) mvpOut[tid] = s_mvp[tid];
        if (tid == 0) *doneCnt = 0u;
    }

    if (xc == 0)
        depthBits[g] = depth_bits(g, view[8], view[9], view[10], view[11]);

    unsigned c = 0;
    int x0 = xc * XCW;
    #pragma unroll
    for (int j = 0; j < XCW; ++j) {
        float occ;
        if (voxel_valid(x0 + j, g, occL, s_mvp, &occ)) ++c;
    }
    g16[(size_t)g * 16 + 4 + xc] = (unsigned char)c;
}

// K2: parallel count-sum (72 blocks) + last-block-done selection.
// Last block: BATCHED contiguous count loads (18 u32/thread, branch-free) +
// depth precomputed into registers -> radix passes run memory-free.
__global__ __launch_bounds__(256, 1) void k_sumsel(
    const float* __restrict__ view, const float* __restrict__ proj,
    const float* __restrict__ occL,
    const unsigned char* __restrict__ g16,
    unsigned char* __restrict__ cnt8sum,
    unsigned* __restrict__ doneCnt,
    const int* __restrict__ maxBlocksPtr,
    unsigned* __restrict__ sel,
    unsigned* __restrict__ tiedList,
    unsigned* __restrict__ tiedPrefX,
    unsigned* __restrict__ nTiedG)
{
    __shared__ unsigned s_last;
    __shared__ float s_mvp[16];
    __shared__ unsigned s_h[256];
    __shared__ unsigned s_w[4];
    __shared__ unsigned s_tot;
    __shared__ unsigned s_prefix, s_remK;
    __shared__ unsigned s_list[256];
    __shared__ int s_n;
    __shared__ unsigned s_cntX[GX];

    int tid = threadIdx.x;
    int g0  = blockIdx.x * 256 + tid;

    // parallel part: sum 12 u8 partials -> one u8 per group
    uint4 q = *(const uint4*)(g16 + (size_t)g0 * 16);
    cnt8sum[g0] = (unsigned char)(BSUM(q.y) + BSUM(q.z) + BSUM(q.w));

    __threadfence();
    if (tid == 0) {
        unsigned old = atomicAdd(doneCnt, 1u);
        s_last = (old == SB - 1) ? 1u : 0u;
    }
    __syncthreads();
    if (!s_last) return;
    __threadfence();                       // acquire: see all blocks' cnt8sum

    // ---- last block: full selection (contiguous remap: thread t owns
    //      groups [t*72, t*72+72); histogram is mapping-invariant) ----
    compute_mvp_lds(view, proj, s_mvp, tid);
    float v8 = view[8], v9 = view[9], v10 = view[10], v11 = view[11];
    int lane = tid & 63;
    int wid  = tid >> 6;
    unsigned K = (unsigned)maxBlocksPtr[0];
    int base = tid * SGPT;

    // batched branch-free count load: 18 contiguous u32 (= 72 u8)
    unsigned cw[SGPT / 4];
    {
        const unsigned* cp = (const unsigned*)(cnt8sum) + tid * (SGPT / 4);
        #pragma unroll
        for (int k = 0; k < SGPT / 4; ++k) cw[k] = cp[k];
    }
    // depth bits for own groups, in registers (pure VALU)
    unsigned d[SGPT];
    #pragma unroll
    for (int j = 0; j < SGPT; ++j)
        d[j] = depth_bits(base + j, v8, v9, v10, v11);

    unsigned prefix = 0, remK = K;
    for (int p = 0; p < 4; ++p) {
        int shift = 24 - 8 * p;
        s_h[tid] = 0;
        __syncthreads();
        #pragma unroll
        for (int j = 0; j < SGPT; ++j) {
            unsigned cc = (cw[j >> 2] >> ((j & 3) * 8)) & 255u;
            if (!cc) continue;
            unsigned db = d[j];
            if (p > 0 && (db >> (shift + 8)) != prefix) continue;
            atomicAdd(&s_h[(db >> shift) & 255u], cc);
        }
        __syncthreads();
        unsigned ps = s_h[tid];
        unsigned iw = wave_incl_scan(ps, lane);
        if (lane == 63) s_w[wid] = iw;
        __syncthreads();
        if (wid == 0) {
            unsigned wv = (lane < 4) ? s_w[lane] : 0u;
            unsigned wiw = wave_incl_scan(wv, lane);
            if (lane < 4) s_w[lane] = wiw - wv;   // exclusive wave offset
            if (lane == 3) s_tot = wiw;           // pass total
        }
        __syncthreads();
        unsigned incl = iw + s_w[wid];
        unsigned excl = incl - ps;

        if (p == 0) {
            if (s_tot <= K) {                     // keep all valid (uniform)
                if (tid == 0) {
                    sel[0] = 0xFFFFFFFFu;
                    sel[1] = 0x7FFFFFFFu;
                    *nTiedG = 0u;
                }
                return;
            }
        }
        if (excl < remK && remK <= incl) {        // unique crossing thread
            s_prefix = (prefix << 8) | (unsigned)tid;
            s_remK   = remK - excl;
        }
        __syncthreads();
        prefix = s_prefix; remK = s_remK;
        __syncthreads();
    }
    unsigned T = prefix;                          // threshold depth bits
    unsigned R = remK;                            // quota at exactly T

    // tied groups: sorted list + per-x valid prefix (occL recompute)
    if (tid == 0) s_n = 0;
    if (tid < GX) s_cntX[tid] = 0;
    __syncthreads();
    #pragma unroll
    for (int j = 0; j < SGPT; ++j) {
        if (d[j] == T) {
            int idx = atomicAdd(&s_n, 1);
            if (idx < 256) s_list[idx] = (unsigned)(base + j);
        }
    }
    __syncthreads();
    int n = min(s_n, 256);
    if (tid == 0) {
        for (int a = 1; a < n; ++a) {             // insertion sort (n tiny)
            unsigned v = s_list[a];
            int b2 = a - 1;
            while (b2 >= 0 && s_list[b2] > v) { s_list[b2 + 1] = s_list[b2]; --b2; }
            s_list[b2 + 1] = v;
        }
    }
    __syncthreads();
    int pairs = GX * n;
    for (int pr = tid; pr < pairs; pr += 256) {
        int x = pr / n;
        int s = pr - x * n;
        float occ;
        if (voxel_valid(x, (int)s_list[s], occL, s_mvp, &occ))
            atomicAdd(&s_cntX[x], 1u);
    }
    __syncthreads();
    if (tid == 0) {
        unsigned run = 0;
        for (int x = 0; x < GX; ++x) { tiedPrefX[x] = run; run += s_cntX[x]; }
        *nTiedG = (unsigned)n;
        sel[0] = T;
        sel[1] = R;
    }
    if (tid < n) tiedList[tid] = s_list[tid];
}

// K3: output — R5-exact body (recompute predicate from occL; NT loads/stores).
__global__ __launch_bounds__(256) void k_out(
    const float* __restrict__ occL,
    const float* __restrict__ matL,
    const float* __restrict__ mvp,
    const unsigned* __restrict__ depthBits,
    const unsigned* __restrict__ sel,
    const unsigned* __restrict__ tiedList,
    const unsigned* __restrict__ tiedPrefX,
    const unsigned* __restrict__ nTiedPtr,
    float* __restrict__ out)
{
    int i = blockIdx.x * 256 + threadIdx.x;
    if (i >= NVOX) return;
    int x = i / GRP;
    int g = i - x * GRP;

    float occ;
    bool valid = voxel_valid(x, g, occL, mvp, &occ);
    bool keep = false;
    if (valid) {
        unsigned T  = sel[0];
        unsigned db = depthBits[g];
        if (db < T) {
            keep = true;
        } else if (db == T) {
            unsigned R = sel[1];
            unsigned rank = tiedPrefX[x];
            int n = (int)*nTiedPtr;
            for (int s = 0; s < n; ++s) {
                unsigned gs = tiedList[s];
                if (gs >= (unsigned)g) break;
                float o2;
                if (voxel_valid(x, (int)gs, occL, mvp, &o2)) ++rank;
            }
            keep = rank < R;
        }
    }

    f4 o0 = (f4)(0.0f);
    f4 o1 = (f4)(0.0f);
    if (keep) {
        const f4* mp = reinterpret_cast<const f4*>(matL) + (size_t)i * 2;
        f4 a = __builtin_nontemporal_load(mp);
        f4 b = __builtin_nontemporal_load(mp + 1);
        float mx = fmaxf(fmaxf(fmaxf(a[0], a[1]), fmaxf(a[2], a[3])),
                         fmaxf(fmaxf(b[0], b[1]), fmaxf(b[2], b[3])));
        float e0 = expf(a[0] - mx), e1 = expf(a[1] - mx), e2 = expf(a[2] - mx), e3 = expf(a[3] - mx);
        float e4 = expf(b[0] - mx), e5 = expf(b[1] - mx), e6 = expf(b[2] - mx), e7 = expf(b[3] - mx);
        float s = ((e0 + e1) + (e2 + e3)) + ((e4 + e5) + (e6 + e7));
        float inv = occ / s;
        o0[0] = e0 * inv; o0[1] = e1 * inv; o0[2] = e2 * inv; o0[3] = e3 * inv;
        o1[0] = e4 * inv; o1[1] = e5 * inv; o1[2] = e6 * inv; o1[3] = e7 * inv;
    }
    f4* op = reinterpret_cast<f4*>(out) + (size_t)i * 2;
    __builtin_nontemporal_store(o0, op);
    __builtin_nontemporal_store(o1, op + 1);
}

extern "C" void kernel_launch(void* const* d_in, const int* in_sizes, int n_in,
                              void* d_out, int out_size, void* d_ws, size_t ws_size,
                              hipStream_t stream)
{
    const float* occL = (const float*)d_in[0];
    const float* matL = (const float*)d_in[1];
    const float* view = (const float*)d_in[2];
    const float* proj = (const float*)d_in[3];
    const int*   mb   = (const int*)d_in[4];

    char* ws = (char*)d_ws;
    float*          mvp      = (float*)(ws + WS_MVP);
    unsigned char*  g16      = (unsigned char*)(ws + WS_G16);
    unsigned*       depthB   = (unsigned*)(ws + WS_DEPTH);
    unsigned char*  csum     = (unsigned char*)(ws + WS_CSUM);
    unsigned*       done     = (unsigned*)(ws + WS_DONE);
    unsigned*       sel      = (unsigned*)(ws + WS_SEL);
    unsigned*       tiedList = (unsigned*)(ws + WS_TLIST);
    unsigned*       tiedPref = (unsigned*)(ws + WS_TPREF);
    unsigned*       nTied    = (unsigned*)(ws + WS_NTIED);

    k_prep_count<<<NXC * GBLK, 256, 0, stream>>>(view, proj, occL, mvp, g16, depthB, done);
    k_sumsel<<<SB, 256, 0, stream>>>(view, proj, occL, g16, csum, done, mb,
                                     sel, tiedList, tiedPref, nTied);
    k_out<<<NVOX / 256, 256, 0, stream>>>(occL, matL, mvp, depthB, sel,
                                          tiedList, tiedPref, nTied, (float*)d_out);
}

// Round 13
// 85.159 us; speedup vs baseline: 1.3388x; 1.0694x over previous
//
#include <hip/hip_runtime.h>

#define GX 192
#define GY 96
#define GZ 192
#define GRP (GY*GZ)            // 18432 (y,z) groups
#define NVOX (GX*GRP)          // 3538944 voxels

#define NXC 12                 // x-chunks in prep
#define XCW (GX/NXC)           // 16 voxels per thread/chunk
#define GBLK (GRP/256)         // 72 blocks per chunk

#define SB   (GRP/256)         // 72 sum/select blocks
#define SGPT (GRP/256)         // 72 groups per thread in select (contiguous)

// workspace byte offsets
#define WS_MVP    0                        // 16 floats
#define WS_G16    64                       // GRP x 16B records {pad u32, u8 cnt[12]}
#define WS_DEPTH  (WS_G16 + (size_t)GRP*16)// GRP u32 depth bits (for k_out)
#define WS_CSUM   (WS_DEPTH + GRP*4)       // GRP u8 summed counts
#define WS_DONE   (WS_CSUM + GRP)          // 1 u32 block-done counter
#define WS_SEL    (WS_DONE + 16)           // 2 u32: T, R
#define WS_TLIST  (WS_SEL + 16)            // 256 u32 tied group ids (sorted)
#define WS_TPREF  (WS_TLIST + 1024)        // GX u32 excl prefix of tied-valid per x
#define WS_NTIED  (WS_TPREF + GX*4)        // 1 u32

typedef float f4 __attribute__((ext_vector_type(4)));

#define BSUM(w) (((w) & 255u) + (((w) >> 8) & 255u) + (((w) >> 16) & 255u) + ((w) >> 24))

// Replicate reference fp32 arithmetic exactly:
//   clip_c = fma(cz, M[c][2], fma(cy, M[c][1], cx*M[c][0])) + M[c][3]
__device__ __forceinline__ bool voxel_valid(int x, int g,
                                            const float* __restrict__ occL,
                                            const float* M,
                                            float* occ_out)
{
    int y = g / GZ;
    int z = g - y * GZ;
    float cx = (float)(2 * x - 191);
    float cy = (float)(2 * y + 1);
    float cz = (float)(2 * z - 191);

    float logit = occL[(size_t)x * GRP + g];
    float occ = 1.0f / (1.0f + expf(-logit));
    *occ_out = occ;
    if (!(occ > 0.01f)) return false;

    float c0 = __fadd_rn(__fmaf_rn(cz, M[2],  __fmaf_rn(cy, M[1],  __fmul_rn(cx, M[0]))),  M[3]);
    float c1 = __fadd_rn(__fmaf_rn(cz, M[6],  __fmaf_rn(cy, M[5],  __fmul_rn(cx, M[4]))),  M[7]);
    float c2 = __fadd_rn(__fmaf_rn(cz, M[10], __fmaf_rn(cy, M[9],  __fmul_rn(cx, M[8]))),  M[11]);
    float c3 = __fadd_rn(__fmaf_rn(cz, M[14], __fmaf_rn(cy, M[13], __fmul_rn(cx, M[12]))), M[15]);

    float w  = fmaxf(c3, 1e-6f);
    float nx = c0 / w;
    float ny = c1 / w;
    float nz = c2 / w;
    return (nx >= -1.0f) && (nx <= 1.0f) &&
           (ny >= -1.0f) && (ny <= 1.0f) &&
           (nz >= -1.0f) && (nz <= 1.0f);
}

// depth bits for group g — identical pinned-FMA expression everywhere.
__device__ __forceinline__ unsigned depth_bits(int g, float v8, float v9,
                                               float v10, float v11)
{
    int y = g / GZ;
    int z = g - y * GZ;
    float cy = (float)(2 * y + 1);
    float cz = (float)(2 * z - 191);
    float seed = __fmul_rn(-191.0f, v8);
    float vz = __fadd_rn(__fmaf_rn(cz, v10, __fmaf_rn(cy, v9, seed)), v11);
    return __float_as_uint(fmaxf(-vz, 0.0f));   // >= 0: bits order-monotone
}

__device__ __forceinline__ void compute_mvp_lds(const float* view, const float* proj,
                                                float* s_mvp, int tid)
{
    if (tid < 16) {
        int r = tid >> 2, c = tid & 3;
        float acc = 0.0f;
        for (int k = 0; k < 4; ++k)
            acc = __fadd_rn(acc, __fmul_rn(proj[r * 4 + k], view[k * 4 + c]));
        s_mvp[tid] = acc;
    }
}

__device__ __forceinline__ unsigned wave_incl_scan(unsigned v, int lane)
{
    #pragma unroll
    for (int off = 1; off < 64; off <<= 1) {
        unsigned u = (unsigned)__shfl_up((int)v, off);
        if (lane >= off) v += u;
    }
    return v;
}

// K1: mvp (block 0), done-counter zero (block 0), depth bits (xc==0),
// u8 partial valid counts into bytes 4..15 of the 16B group record.
__global__ __launch_bounds__(256) void k_prep_count(
    const float* __restrict__ view, const float* __restrict__ proj,
    const float* __restrict__ occL,
    float* __restrict__ mvpOut,
    unsigned char* __restrict__ g16,
    unsigned* __restrict__ depthBits,
    unsigned* __restrict__ doneCnt)
{
    __shared__ float s_mvp[16];
    int tid = threadIdx.x;
    compute_mvp_lds(view, proj, s_mvp, tid);
    __syncthreads();

    int b  = blockIdx.x;
    int gb = b % GBLK;
    int xc = b / GBLK;
    int g  = gb * 256 + tid;

    if (b == 0) {
        if (tid < 16) mvpOut[tid] = s_mvp[tid];
        if (tid == 0) *doneCnt = 0u;
    }

    if (xc == 0)
        depthBits[g] = depth_bits(g, view[8], view[9], view[10], view[11]);

    unsigned c = 0;
    int x0 = xc * XCW;
    #pragma unroll
    for (int j = 0; j < XCW; ++j) {
        float occ;
        if (voxel_valid(x0 + j, g, occL, s_mvp, &occ)) ++c;
    }
    g16[(size_t)g * 16 + 4 + xc] = (unsigned char)c;
}

// K2: parallel count-sum (72 blocks) + last-block-done selection.
// Last block: batched contiguous count loads + register depth bits +
// LANE-REPLICATED histogram s_h64[bin][64] -> no same-address atomic storm
// (same-wave lanes hit distinct addresses; cross-wave collisions <= 4-way).
__global__ __launch_bounds__(256, 1) void k_sumsel(
    const float* __restrict__ view, const float* __restrict__ proj,
    const float* __restrict__ occL,
    const unsigned char* __restrict__ g16,
    unsigned char* __restrict__ cnt8sum,
    unsigned* __restrict__ doneCnt,
    const int* __restrict__ maxBlocksPtr,
    unsigned* __restrict__ sel,
    unsigned* __restrict__ tiedList,
    unsigned* __restrict__ tiedPrefX,
    unsigned* __restrict__ nTiedG)
{
    __shared__ unsigned s_last;
    __shared__ float s_mvp[16];
    __shared__ unsigned s_h64[256 * 64];   // 64 KB: [bin][lane] replicated hist
    __shared__ unsigned s_w[4];
    __shared__ unsigned s_tot;
    __shared__ unsigned s_prefix, s_remK;
    __shared__ unsigned s_list[256];
    __shared__ int s_n;
    __shared__ unsigned s_cntX[GX];

    int tid = threadIdx.x;
    int g0  = blockIdx.x * 256 + tid;

    // parallel part: sum 12 u8 partials -> one u8 per group
    uint4 q = *(const uint4*)(g16 + (size_t)g0 * 16);
    cnt8sum[g0] = (unsigned char)(BSUM(q.y) + BSUM(q.z) + BSUM(q.w));

    __threadfence();
    if (tid == 0) {
        unsigned old = atomicAdd(doneCnt, 1u);
        s_last = (old == SB - 1) ? 1u : 0u;
    }
    __syncthreads();
    if (!s_last) return;
    __threadfence();                       // acquire: see all blocks' cnt8sum

    // ---- last block: full selection (contiguous remap: thread t owns
    //      groups [t*72, t*72+72); histogram is mapping-invariant) ----
    compute_mvp_lds(view, proj, s_mvp, tid);
    float v8 = view[8], v9 = view[9], v10 = view[10], v11 = view[11];
    int lane = tid & 63;
    int wid  = tid >> 6;
    unsigned K = (unsigned)maxBlocksPtr[0];
    int base = tid * SGPT;

    // batched branch-free count load: 18 contiguous u32 (= 72 u8)
    unsigned cw[SGPT / 4];
    {
        const unsigned* cp = (const unsigned*)(cnt8sum) + tid * (SGPT / 4);
        #pragma unroll
        for (int k = 0; k < SGPT / 4; ++k) cw[k] = cp[k];
    }
    // depth bits for own groups, in registers (pure VALU)
    unsigned d[SGPT];
    #pragma unroll
    for (int j = 0; j < SGPT; ++j)
        d[j] = depth_bits(base + j, v8, v9, v10, v11);

    unsigned prefix = 0, remK = K;
    for (int p = 0; p < 4; ++p) {
        int shift = 24 - 8 * p;
        // zero the replicated histogram (16 x uint4 per thread)
        {
            uint4* z = (uint4*)s_h64;
            #pragma unroll
            for (int j = 0; j < 16; ++j)
                z[tid + j * 256] = make_uint4(0u, 0u, 0u, 0u);
        }
        __syncthreads();
        #pragma unroll
        for (int j = 0; j < SGPT; ++j) {
            unsigned cc = (cw[j >> 2] >> ((j & 3) * 8)) & 255u;
            if (!cc) continue;
            unsigned db = d[j];
            if (p > 0 && (db >> (shift + 8)) != prefix) continue;
            atomicAdd(&s_h64[(((db >> shift) & 255u) << 6) | lane], cc);
        }
        __syncthreads();
        // per-bin total: thread tid owns bin tid; staggered reads (2-way max)
        unsigned ps = 0;
        #pragma unroll
        for (int j = 0; j < 64; ++j) {
            int jj = (j + lane) & 63;
            ps += s_h64[(tid << 6) | jj];
        }
        unsigned iw = wave_incl_scan(ps, lane);
        if (lane == 63) s_w[wid] = iw;
        __syncthreads();
        if (wid == 0) {
            unsigned wv = (lane < 4) ? s_w[lane] : 0u;
            unsigned wiw = wave_incl_scan(wv, lane);
            if (lane < 4) s_w[lane] = wiw - wv;   // exclusive wave offset
            if (lane == 3) s_tot = wiw;           // pass total
        }
        __syncthreads();
        unsigned incl = iw + s_w[wid];
        unsigned excl = incl - ps;

        if (p == 0) {
            if (s_tot <= K) {                     // keep all valid (uniform)
                if (tid == 0) {
                    sel[0] = 0xFFFFFFFFu;
                    sel[1] = 0x7FFFFFFFu;
                    *nTiedG = 0u;
                }
                return;
            }
        }
        if (excl < remK && remK <= incl) {        // unique crossing thread
            s_prefix = (prefix << 8) | (unsigned)tid;
            s_remK   = remK - excl;
        }
        __syncthreads();
        prefix = s_prefix; remK = s_remK;
        __syncthreads();
    }
    unsigned T = prefix;                          // threshold depth bits
    unsigned R = remK;                            // quota at exactly T

    // tied groups: sorted list + per-x valid prefix (occL recompute)
    if (tid == 0) s_n = 0;
    if (tid < GX) s_cntX[tid] = 0;
    __syncthreads();
    #pragma unroll
    for (int j = 0; j < SGPT; ++j) {
        if (d[j] == T) {
            int idx = atomicAdd(&s_n, 1);
            if (idx < 256) s_list[idx] = (unsigned)(base + j);
        }
    }
    __syncthreads();
    int n = min(s_n, 256);
    if (tid == 0) {
        for (int a = 1; a < n; ++a) {             // insertion sort (n tiny)
            unsigned v = s_list[a];
            int b2 = a - 1;
            while (b2 >= 0 && s_list[b2] > v) { s_list[b2 + 1] = s_list[b2]; --b2; }
            s_list[b2 + 1] = v;
        }
    }
    __syncthreads();
    int pairs = GX * n;
    for (int pr = tid; pr < pairs; pr += 256) {
        int x = pr / n;
        int s = pr - x * n;
        float occ;
        if (voxel_valid(x, (int)s_list[s], occL, s_mvp, &occ))
            atomicAdd(&s_cntX[x], 1u);
    }
    __syncthreads();
    if (tid == 0) {
        unsigned run = 0;
        for (int x = 0; x < GX; ++x) { tiedPrefX[x] = run; run += s_cntX[x]; }
        *nTiedG = (unsigned)n;
        sel[0] = T;
        sel[1] = R;
    }
    if (tid < n) tiedList[tid] = s_list[tid];
}

// K3: output — R5-exact body (recompute predicate from occL; NT loads/stores).
__global__ __launch_bounds__(256) void k_out(
    const float* __restrict__ occL,
    const float* __restrict__ matL,
    const float* __restrict__ mvp,
    const unsigned* __restrict__ depthBits,
    const unsigned* __restrict__ sel,
    const unsigned* __restrict__ tiedList,
    const unsigned* __restrict__ tiedPrefX,
    const unsigned* __restrict__ nTiedPtr,
    float* __restrict__ out)
{
    int i = blockIdx.x * 256 + threadIdx.x;
    if (i >= NVOX) return;
    int x = i / GRP;
    int g = i - x * GRP;

    float occ;
    bool valid = voxel_valid(x, g, occL, mvp, &occ);
    bool keep = false;
    if (valid) {
        unsigned T  = sel[0];
        unsigned db = depthBits[g];
        if (db < T) {
            keep = true;
        } else if (db == T) {
            unsigned R = sel[1];
            unsigned rank = tiedPrefX[x];
            int n = (int)*nTiedPtr;
            for (int s = 0; s < n; ++s) {
                unsigned gs = tiedList[s];
                if (gs >= (unsigned)g) break;
                float o2;
                if (voxel_valid(x, (int)gs, occL, mvp, &o2)) ++rank;
            }
            keep = rank < R;
        }
    }

    f4 o0 = (f4)(0.0f);
    f4 o1 = (f4)(0.0f);
    if (keep) {
        const f4* mp = reinterpret_cast<const f4*>(matL) + (size_t)i * 2;
        f4 a = __builtin_nontemporal_load(mp);
        f4 b = __builtin_nontemporal_load(mp + 1);
        float mx = fmaxf(fmaxf(fmaxf(a[0], a[1]), fmaxf(a[2], a[3])),
                         fmaxf(fmaxf(b[0], b[1]), fmaxf(b[2], b[3])));
        float e0 = expf(a[0] - mx), e1 = expf(a[1] - mx), e2 = expf(a[2] - mx), e3 = expf(a[3] - mx);
        float e4 = expf(b[0] - mx), e5 = expf(b[1] - mx), e6 = expf(b[2] - mx), e7 = expf(b[3] - mx);
        float s = ((e0 + e1) + (e2 + e3)) + ((e4 + e5) + (e6 + e7));
        float inv = occ / s;
        o0[0] = e0 * inv; o0[1] = e1 * inv; o0[2] = e2 * inv; o0[3] = e3 * inv;
        o1[0] = e4 * inv; o1[1] = e5 * inv; o1[2] = e6 * inv; o1[3] = e7 * inv;
    }
    f4* op = reinterpret_cast<f4*>(out) + (size_t)i * 2;
    __builtin_nontemporal_store(o0, op);
    __builtin_nontemporal_store(o1, op + 1);
}

extern "C" void kernel_launch(void* const* d_in, const int* in_sizes, int n_in,
                              void* d_out, int out_size, void* d_ws, size_t ws_size,
                              hipStream_t stream)
{
    const float* occL = (const float*)d_in[0];
    const float* matL = (const float*)d_in[1];
    const float* view = (const float*)d_in[2];
    const float* proj = (const float*)d_in[3];
    const int*   mb   = (const int*)d_in[4];

    char* ws = (char*)d_ws;
    float*          mvp      = (float*)(ws + WS_MVP);
    unsigned char*  g16      = (unsigned char*)(ws + WS_G16);
    unsigned*       depthB   = (unsigned*)(ws + WS_DEPTH);
    unsigned char*  csum     = (unsigned char*)(ws + WS_CSUM);
    unsigned*       done     = (unsigned*)(ws + WS_DONE);
    unsigned*       sel      = (unsigned*)(ws + WS_SEL);
    unsigned*       tiedList = (unsigned*)(ws + WS_TLIST);
    unsigned*       tiedPref = (unsigned*)(ws + WS_TPREF);
    unsigned*       nTied    = (unsigned*)(ws + WS_NTIED);

    k_prep_count<<<NXC * GBLK, 256, 0, stream>>>(view, proj, occL, mvp, g16, depthB, done);
    k_sumsel<<<SB, 256, 0, stream>>>(view, proj, occL, g16, csum, done, mb,
                                     sel, tiedList, tiedPref, nTied);
    k_out<<<NVOX / 256, 256, 0, stream>>>(occL, matL, mvp, depthB, sel,
                                          tiedList, tiedPref, nTied, (float*)d_out);
}